// Round 1
// baseline (830.288 us; speedup 1.0000x reference)
//
#include <hip/hip_runtime.h>
#include <math.h>

#define HDIM 4096
#define NEXP 64
#define NTOK 16384
#define MB   64     // tokens per block
#define KC   64     // k-chunk staged in LDS

// Main kernel: fused GEMM (logits) + softmax + top-2 + per-block loss partials.
// Layout: 256 threads = 4 waves. Wave w owns experts [16w,16w+16) (gate rows read
// via wave-uniform scalar loads). Lane l owns token m0+l. A-tile staged transposed
// in LDS (stride 65 -> conflict-free), register-prefetched one chunk ahead.
__global__ __launch_bounds__(256) void router_main(
    const float* __restrict__ hidden,
    const float* __restrict__ gate,
    float* __restrict__ out_rw,    // [NTOK*2]
    float* __restrict__ out_sel,   // [NTOK*2] indices as floats
    float* __restrict__ psum_g,    // [64] sum of probs per expert
    float* __restrict__ cnt_g,     // [64] selection counts per expert (as float)
    float* __restrict__ zsum_g)    // [1] sum of lse^2
{
    __shared__ float A_lds[KC * 65];
    __shared__ float C_lds[MB * 65];
    __shared__ float rden[MB];
    __shared__ unsigned hist[NEXP];

    const int t = threadIdx.x;
    const int lane = t & 63;
    const int wave = __builtin_amdgcn_readfirstlane(t >> 6);   // force SGPR
    const int m0 = blockIdx.x * MB;
    const float* __restrict__ gp = gate + (size_t)wave * 16 * HDIM;

    float acc[16];
#pragma unroll
    for (int j = 0; j < 16; ++j) acc[j] = 0.f;

    const float4* __restrict__ A4 = (const float4*)hidden;
    float4 pref[4];
#pragma unroll
    for (int i = 0; i < 4; ++i) {
        int idx = t + 256 * i;
        int m = idx >> 4, kq = idx & 15;
        pref[i] = A4[(size_t)(m0 + m) * (HDIM / 4) + kq];
    }

    for (int kc = 0; kc < HDIM / KC; ++kc) {
        // store prefetched A tile to LDS, transposed: A_lds[k][m]
#pragma unroll
        for (int i = 0; i < 4; ++i) {
            int idx = t + 256 * i;
            int m = idx >> 4, kq = idx & 15;
            A_lds[(4 * kq + 0) * 65 + m] = pref[i].x;
            A_lds[(4 * kq + 1) * 65 + m] = pref[i].y;
            A_lds[(4 * kq + 2) * 65 + m] = pref[i].z;
            A_lds[(4 * kq + 3) * 65 + m] = pref[i].w;
        }
        __syncthreads();
        // issue next chunk's global loads early; compute hides the latency
        if (kc + 1 < HDIM / KC) {
            int cb = (kc + 1) * (KC / 4);
#pragma unroll
            for (int i = 0; i < 4; ++i) {
                int idx = t + 256 * i;
                int m = idx >> 4, kq = idx & 15;
                pref[i] = A4[(size_t)(m0 + m) * (HDIM / 4) + cb + kq];
            }
        }
        const float* __restrict__ gk = gp + (size_t)kc * KC;
#pragma unroll 4
        for (int k = 0; k < KC; ++k) {
            float a = A_lds[k * 65 + lane];
#pragma unroll
            for (int j = 0; j < 16; ++j)
                acc[j] = fmaf(a, gk[(size_t)j * HDIM + k], acc[j]);  // gate: uniform addr -> s_load
        }
        __syncthreads();
    }

    // logits -> C_lds[token(lane)][expert]
#pragma unroll
    for (int j = 0; j < 16; ++j)
        C_lds[lane * 65 + wave * 16 + j] = acc[j];
    if (t < NEXP) hist[t] = 0u;
    __syncthreads();

    if (wave != 0) return;   // epilogue on wave 0 only (no barriers after this)

    // pass A: top-2 over experts (strict > , ascending e => ties pick lower index, matches jax)
    float v1 = -INFINITY, v2 = -INFINITY;
    int i1 = 0, i2 = 0;
    for (int e = 0; e < NEXP; ++e) {
        float v = C_lds[lane * 65 + e];
        if (v > v1)      { v2 = v1; i2 = i1; v1 = v; i1 = e; }
        else if (v > v2) { v2 = v;  i2 = e; }
    }
    atomicAdd(&hist[i1], 1u);
    atomicAdd(&hist[i2], 1u);

    // pass B: softmax denom, z-loss, outputs
    float d = 0.f;
    for (int e = 0; e < NEXP; ++e) {
        float ev = expf(C_lds[lane * 65 + e] - v1);
        C_lds[lane * 65 + e] = ev;   // keep exp for pass C
        d += ev;
    }
    rden[lane] = 1.0f / d;
    float lse = v1 + logf(d);
    float z = lse * lse;

    float e2 = expf(v2 - v1);
    float w2 = e2 / (1.f + e2);      // == p2/(p1+p2)
    float w1 = 1.f - w2;
    int tok = m0 + lane;
    out_rw[2 * tok + 0] = w1;
    out_rw[2 * tok + 1] = w2;
    out_sel[2 * tok + 0] = (float)i1;
    out_sel[2 * tok + 1] = (float)i2;

#pragma unroll
    for (int off = 32; off > 0; off >>= 1) z += __shfl_down(z, off);
    if (lane == 0) atomicAdd(zsum_g, z);

    // pass C: per-expert prob sums over this block's 64 tokens (lane = expert)
    float ps = 0.f;
    for (int m = 0; m < MB; ++m)
        ps += C_lds[m * 65 + lane] * rden[m];
    atomicAdd(&psum_g[lane], ps);
    atomicAdd(&cnt_g[lane], (float)hist[lane]);
}

// Combine per-expert partials into the scalar router loss.
__global__ void router_final(const float* __restrict__ ws, float* __restrict__ out_loss)
{
    int e = threadIdx.x;  // 64 threads
    const float inv = 1.0f / (float)NTOK;
    float p = (ws[64 + e] * inv) * (ws[e] * inv);   // tokens_per_expert * prob_per_expert
#pragma unroll
    for (int off = 32; off > 0; off >>= 1) p += __shfl_down(p, off);
    if (e == 0)
        out_loss[0] = 0.01f * (64.f * p) + 0.001f * (ws[128] * inv);
}

extern "C" void kernel_launch(void* const* d_in, const int* in_sizes, int n_in,
                              void* d_out, int out_size, void* d_ws, size_t ws_size,
                              hipStream_t stream) {
    const float* hidden = (const float*)d_in[0];   // [4,4096,4096] fp32
    const float* gate   = (const float*)d_in[1];   // [64,4096] fp32
    float* out = (float*)d_out;                    // 65537 floats
    float* ws  = (float*)d_ws;                     // psum[64] | cnt[64] | zsum[1]

    hipMemsetAsync(d_ws, 0, 129 * sizeof(float), stream);
    router_main<<<dim3(NTOK / MB), dim3(256), 0, stream>>>(
        hidden, gate,
        out,                 // routing weights
        out + NTOK * 2,      // selected experts (as float)
        ws, ws + 64, ws + 128);
    router_final<<<dim3(1), dim3(64), 0, stream>>>(ws, out + NTOK * 4);
}